// Round 8
// baseline (263.108 us; speedup 1.0000x reference)
//
#include <hip/hip_runtime.h>
#include <math.h>

#define NTOK 16384      // 4 * 4096 tokens
#define DIM 2048
#define NEXP 64
#define TOPK 8
#define BT 64           // tokens per block (lane = token)
#define KC 64           // four numpy 16-blocks per LDS stage (processed in order)
#define NCHUNK (DIM / KC)   // 32
#define PADK 68         // LDS row stride (floats); 272B row, 16B-aligned
#define NBLK (NTOK / BT)    // 256 blocks
#define EPW 8           // experts per wave (8 waves x 8 = 64)

typedef float f4 __attribute__((ext_vector_type(4)));

__global__ __launch_bounds__(512, 1) void moe_gate_np(
    const float* __restrict__ h, const float* __restrict__ W,
    float* __restrict__ out, float* __restrict__ wsum)
{
#pragma clang fp contract(off)
    __shared__ float sA[BT * PADK];          // h tile [64][68]
    __shared__ float lg[BT][NEXP + 2];       // logits -> p values

    const int tid  = threadIdx.x;            // 0..511
    const int blk  = blockIdx.x;
    const int lane = tid & 63;               // token within tile
    const int wv   = tid >> 6;               // 0..7: expert group
    const long tok0 = (long)blk * BT;
    const float* hA = h + tok0 * DIM;

    // wave-uniform expert base -> scalar (s_load) W accesses
    const int ewv = __builtin_amdgcn_readfirstlane(wv);
    const float* wbase = W + (long)ewv * EPW * DIM;

    // ---- A staging map: 2 float4 per thread per stage ----
    const int i0 = tid,        r0 = i0 >> 4, c0 = (i0 & 15) * 4;
    const int i1 = tid + 512,  r1 = i1 >> 4, c1 = (i1 & 15) * 4;

    f4 pa0 = *(const f4*)(hA + (long)r0 * DIM + c0);
    f4 pa1 = *(const f4*)(hA + (long)r1 * DIM + c1);

    // accumulators: 8 experts x 4 numpy stride-4 chains
    float acc[EPW][4];
    #pragma unroll
    for (int j = 0; j < EPW; ++j)
        #pragma unroll
        for (int m = 0; m < 4; ++m) acc[j][m] = 0.f;

    for (int kc = 0; kc < NCHUNK; ++kc) {
        __syncthreads();
        *(f4*)&sA[r0 * PADK + c0] = pa0;
        *(f4*)&sA[r1 * PADK + c1] = pa1;
        __syncthreads();

        if (kc + 1 < NCHUNK) {               // prefetch next stage under compute
            const long ko = (long)(kc + 1) * KC;
            pa0 = *(const f4*)(hA + (long)r0 * DIM + ko + c0);
            pa1 = *(const f4*)(hA + (long)r1 * DIM + ko + c1);
        }

        // 4 numpy 16-blocks per stage, strictly ascending k
        #pragma unroll
        for (int s = 0; s < 4; ++s) {
            f4 af[4];                        // this lane's token, 16 k-values
            const float* ab = &sA[lane * PADK + s * 16];
            #pragma unroll
            for (int v = 0; v < 4; ++v) af[v] = *(const f4*)(ab + 4 * v);

            const int kg = kc * KC + s * 16;
            #pragma unroll
            for (int j = 0; j < EPW; ++j) {
                const float* wr = wbase + (long)j * DIM + kg;   // uniform -> s_load
                const f4 b0 = *(const f4*)(wr);
                const f4 b1 = *(const f4*)(wr + 4);
                const f4 b2 = *(const f4*)(wr + 8);
                const f4 b3 = *(const f4*)(wr + 12);
                float t;
                // chain m: c = p0 + (p1 + (p2 + (p3 + c))), p_v = A[4v+m]*B[4v+m]
                t = af[3].x * b3.x + acc[j][0];
                t = af[2].x * b2.x + t;
                t = af[1].x * b1.x + t;
                acc[j][0] = af[0].x * b0.x + t;

                t = af[3].y * b3.y + acc[j][1];
                t = af[2].y * b2.y + t;
                t = af[1].y * b1.y + t;
                acc[j][1] = af[0].y * b0.y + t;

                t = af[3].z * b3.z + acc[j][2];
                t = af[2].z * b2.z + t;
                t = af[1].z * b1.z + t;
                acc[j][2] = af[0].z * b0.z + t;

                t = af[3].w * b3.w + acc[j][3];
                t = af[2].w * b2.w + t;
                t = af[1].w * b1.w + t;
                acc[j][3] = af[0].w * b0.w + t;
            }
        }
    }

    // horizontal combine: (c0+c2)+(c1+c3)  (npyv_sum_f32 SSE2 order)
    __syncthreads();                          // done with sA reads this pass
    #pragma unroll
    for (int j = 0; j < EPW; ++j)
        lg[lane][wv * EPW + j] = (acc[j][0] + acc[j][2]) + (acc[j][1] + acc[j][3]);
    __syncthreads();

    // ---- per-token f32 softmax + stable top-8, numpy rounding orders ----
    float auxacc = 0.f;

    for (int tt = 0; tt < 8; ++tt) {
        const int t = wv * 8 + tt;            // 8 waves x 8 tokens
        const float s = lg[t][lane];          // lane = expert here

        float m = s;                          // max: exact, order-independent
        #pragma unroll
        for (int off = 32; off >= 1; off >>= 1)
            m = fmaxf(m, __shfl_xor(m, off));

        const float p = expf(s - m);
        lg[t][lane] = p;                      // own wave's row only
        __asm__ volatile("" ::: "memory");    // compiler barrier; DS in-order per wave

        // np.sum pairwise, n=64: 8 stride-8 serial chains + fixed combine
        float r0s = lg[t][0], r1s = lg[t][1], r2s = lg[t][2], r3s = lg[t][3];
        float r4s = lg[t][4], r5s = lg[t][5], r6s = lg[t][6], r7s = lg[t][7];
        #pragma unroll
        for (int i = 1; i < 8; ++i) {
            r0s += lg[t][8 * i + 0]; r1s += lg[t][8 * i + 1];
            r2s += lg[t][8 * i + 2]; r3s += lg[t][8 * i + 3];
            r4s += lg[t][8 * i + 4]; r5s += lg[t][8 * i + 5];
            r6s += lg[t][8 * i + 6]; r7s += lg[t][8 * i + 7];
        }
        const float S = ((r0s + r1s) + (r2s + r3s)) + ((r4s + r5s) + (r6s + r7s));

        const float score = p / S;            // IEEE f32 divide, matches np
        auxacc += score;

        // stable top-8: max with lowest-index tie-break (stable argsort)
        float cv = score;
        float myv = 0.f;
        int   myi = 0;
        #pragma unroll
        for (int i = 0; i < TOPK; ++i) {
            float v = cv;
            int idx = lane;
            #pragma unroll
            for (int off = 32; off >= 1; off >>= 1) {
                float v2 = __shfl_xor(v, off);
                int   i2 = __shfl_xor(idx, off);
                if (v2 > v || (v2 == v && i2 < idx)) { v = v2; idx = i2; }
            }
            if (lane == i)   { myv = v; myi = idx; }
            if (lane == idx) cv = -1.f;       // scores >= 0
        }

        // weight denom: np.sum n=8 -> serial ascending
        float S8 = 0.f;
        #pragma unroll
        for (int r = 0; r < TOPK; ++r) S8 += __shfl(myv, r);

        if (lane < TOPK) {
            const long o = (tok0 + t) * TOPK + lane;
            out[o]                     = (float)myi;   // expert_ids
            out[(long)NTOK * TOPK + o] = myv / S8;     // expert_weight
        }
    }

    const int b = blk >> 6;                  // 64 blocks per batch row
    atomicAdd(&wsum[b * NEXP + lane], auxacc);
}

__global__ void aux_finish(const float* __restrict__ wsum, float* __restrict__ out)
{
    const int lane = threadIdx.x;            // 64 threads
    float a = 0.f;
    #pragma unroll
    for (int b = 0; b < 4; ++b) {
        const float v = wsum[b * NEXP + lane] * (1.0f / 4096.0f);
        a = fmaf(v, v, a);
    }
    #pragma unroll
    for (int off = 32; off >= 1; off >>= 1)
        a += __shfl_xor(a, off);
    if (lane == 0)
        out[2L * NTOK * TOPK] = a * 0.25f * (float)NEXP * 0.01f;
}

extern "C" void kernel_launch(void* const* d_in, const int* in_sizes, int n_in,
                              void* d_out, int out_size, void* d_ws, size_t ws_size,
                              hipStream_t stream) {
    const float* h = (const float*)d_in[0];
    const float* W = (const float*)d_in[1];
    float* out  = (float*)d_out;
    float* wsum = (float*)d_ws;              // 256 f32

    hipMemsetAsync(d_ws, 0, 1024, stream);
    moe_gate_np<<<NBLK, 512, 0, stream>>>(h, W, out, wsum);
    aux_finish<<<1, 64, 0, stream>>>(wsum, out);
}

// Round 9
// 246.442 us; speedup vs baseline: 1.0676x; 1.0676x over previous
//
#include <hip/hip_runtime.h>
#include <math.h>

#define NTOK 16384      // 4 * 4096 tokens
#define DIM 2048
#define NEXP 64
#define TOPK 8
#define BT 64           // tokens per block (lane = token)
#define KC 64           // four numpy 16-blocks per stage
#define NCHUNK (DIM / KC)   // 32
#define PADK 68         // LDS row stride (floats)
#define NBLK (NTOK / BT)    // 256 blocks, 1/CU, 8 waves/CU
#define EPW 8           // experts per wave

typedef float f2 __attribute__((ext_vector_type(2)));
typedef float f4 __attribute__((ext_vector_type(4)));

// Packed f32 ops: two independent IEEE f32 ops per instr, component-wise
// bit-identical to the scalar sequence they replace.
__device__ __forceinline__ f2 pk_mul(f2 a, f2 b) {
    f2 d; asm("v_pk_mul_f32 %0, %1, %2" : "=v"(d) : "v"(a), "v"(b)); return d;
}
__device__ __forceinline__ f2 pk_add(f2 a, f2 b) {
    f2 d; asm("v_pk_add_f32 %0, %1, %2" : "=v"(d) : "v"(a), "v"(b)); return d;
}
// broadcast lane sl's f2 to all lanes via readlane (SGPR, wave-uniform)
__device__ __forceinline__ f2 rl2(f2 v, int sl) {
    f2 r;
    r.x = __uint_as_float(__builtin_amdgcn_readlane(__float_as_uint(v.x), sl));
    r.y = __uint_as_float(__builtin_amdgcn_readlane(__float_as_uint(v.y), sl));
    return r;
}

__global__ __launch_bounds__(512, 2) void moe_gate_np(
    const float* __restrict__ h, const float* __restrict__ W,
    float* __restrict__ out, float* __restrict__ wsum)
{
#pragma clang fp contract(off)
    __shared__ float sA[BT * PADK];          // h tile [64][68]
    __shared__ float lg[BT][NEXP + 2];       // logits -> p values

    const int tid  = threadIdx.x;            // 0..511
    const int blk  = blockIdx.x;
    const int lane = tid & 63;               // token within tile
    const int wv   = tid >> 6;               // 0..7: expert octet
    const long tok0 = (long)blk * BT;
    const float* hA = h + tok0 * DIM;
    const int e0 = wv * EPW;

    // ---- A staging map: 2 f4 per thread per stage ----
    const int rs = tid >> 4;                 // 0..31
    const int cs = (tid & 15) * 4;           // 0..60
    f4 pa0 = *(const f4*)(hA + (long)rs * DIM + cs);
    f4 pa1 = *(const f4*)(hA + (long)(rs + 32) * DIM + cs);

    // ---- B cooperative map: lane -> (expert lane>>3, k-pair lane&7) ----
    const float* bp = W + (long)(e0 + (lane >> 3)) * DIM + (lane & 7) * 2;
    f2 pb[4];                                // 4 16-blocks of stage 0
    #pragma unroll
    for (int s = 0; s < 4; ++s) pb[s] = *(const f2*)(bp + s * 16);

    // accumulators: 8 experts x chain pairs (c0,c1) and (c2,c3)
    f2 acc01[EPW], acc23[EPW];
    #pragma unroll
    for (int j = 0; j < EPW; ++j) { acc01[j] = (f2)(0.f); acc23[j] = (f2)(0.f); }

    for (int kc = 0; kc < NCHUNK; ++kc) {
        __syncthreads();
        *(f4*)&sA[rs * PADK + cs]        = pa0;
        *(f4*)&sA[(rs + 32) * PADK + cs] = pa1;
        __syncthreads();

        // snapshot current B regs, then prefetch next stage (A and B)
        f2 cbv[4];
        #pragma unroll
        for (int s = 0; s < 4; ++s) cbv[s] = pb[s];

        if (kc + 1 < NCHUNK) {
            const long ko = (long)(kc + 1) * KC;
            pa0 = *(const f4*)(hA + (long)rs * DIM + ko + cs);
            pa1 = *(const f4*)(hA + (long)(rs + 32) * DIM + ko + cs);
            #pragma unroll
            for (int s = 0; s < 4; ++s) pb[s] = *(const f2*)(bp + ko + s * 16);
        }

        // 4 numpy 16-blocks per stage, strictly ascending k
        #pragma unroll
        for (int s = 0; s < 4; ++s) {
            f4 af[4];                        // this lane's token, 16 k-values
            const float* ab = &sA[lane * PADK + s * 16];
            #pragma unroll
            for (int v = 0; v < 4; ++v) af[v] = *(const f4*)(ab + 4 * v);

            f2 alo[4], ahi[4];               // pairs 2v (chains 0,1) / 2v+1 (2,3)
            #pragma unroll
            for (int v = 0; v < 4; ++v) {
                alo[v] = __builtin_shufflevector(af[v], af[v], 0, 1);
                ahi[v] = __builtin_shufflevector(af[v], af[v], 2, 3);
            }

            #pragma unroll
            for (int j = 0; j < EPW; ++j) {
                const int sb = j * 8;
                // broadcast B pairs for expert j (wave-uniform SGPRs)
                const f2 B0 = rl2(cbv[s], sb + 0);
                const f2 B2 = rl2(cbv[s], sb + 2);
                const f2 B4 = rl2(cbv[s], sb + 4);
                const f2 B6 = rl2(cbv[s], sb + 6);
                const f2 B1 = rl2(cbv[s], sb + 1);
                const f2 B3 = rl2(cbv[s], sb + 3);
                const f2 B5 = rl2(cbv[s], sb + 5);
                const f2 B7 = rl2(cbv[s], sb + 7);
                f2 t;
                // chains 0,1: c = p0 + (p1 + (p2 + (p3 + c)))
                t = pk_add(pk_mul(alo[3], B6), acc01[j]);
                t = pk_add(pk_mul(alo[2], B4), t);
                t = pk_add(pk_mul(alo[1], B2), t);
                acc01[j] = pk_add(pk_mul(alo[0], B0), t);
                // chains 2,3
                t = pk_add(pk_mul(ahi[3], B7), acc23[j]);
                t = pk_add(pk_mul(ahi[2], B5), t);
                t = pk_add(pk_mul(ahi[1], B3), t);
                acc23[j] = pk_add(pk_mul(ahi[0], B1), t);
            }
        }
    }

    // horizontal combine: (c0+c2)+(c1+c3)  (npyv_sum_f32 SSE2 order)
    __syncthreads();                          // sA reads done
    #pragma unroll
    for (int j = 0; j < EPW; ++j) {
        f2 s2 = pk_add(acc01[j], acc23[j]);   // (c0+c2, c1+c3)
        lg[lane][e0 + j] = s2.x + s2.y;
    }
    __syncthreads();

    // ---- per-token f32 softmax + stable top-8, numpy rounding orders ----
    float auxacc = 0.f;

    for (int tt = 0; tt < 8; ++tt) {
        const int t = wv * 8 + tt;            // 8 waves x 8 tokens
        const float s = lg[t][lane];          // lane = expert here

        float m = s;                          // max: exact, order-independent
        #pragma unroll
        for (int off = 32; off >= 1; off >>= 1)
            m = fmaxf(m, __shfl_xor(m, off));

        const float p = expf(s - m);
        lg[t][lane] = p;                      // own wave's row only
        __asm__ volatile("" ::: "memory");    // compiler barrier; DS in-order per wave

        // np.sum pairwise, n=64: 8 stride-8 serial chains + fixed combine
        float r0s = lg[t][0], r1s = lg[t][1], r2s = lg[t][2], r3s = lg[t][3];
        float r4s = lg[t][4], r5s = lg[t][5], r6s = lg[t][6], r7s = lg[t][7];
        #pragma unroll
        for (int i = 1; i < 8; ++i) {
            r0s += lg[t][8 * i + 0]; r1s += lg[t][8 * i + 1];
            r2s += lg[t][8 * i + 2]; r3s += lg[t][8 * i + 3];
            r4s += lg[t][8 * i + 4]; r5s += lg[t][8 * i + 5];
            r6s += lg[t][8 * i + 6]; r7s += lg[t][8 * i + 7];
        }
        const float S = ((r0s + r1s) + (r2s + r3s)) + ((r4s + r5s) + (r6s + r7s));

        const float score = p / S;            // IEEE f32 divide, matches np
        auxacc += score;

        // stable top-8: max with lowest-index tie-break (stable argsort)
        float cv = score;
        float myv = 0.f;
        int   myi = 0;
        #pragma unroll
        for (int i = 0; i < TOPK; ++i) {
            float v = cv;
            int idx = lane;
            #pragma unroll
            for (int off = 32; off >= 1; off >>= 1) {
                float v2 = __shfl_xor(v, off);
                int   i2 = __shfl_xor(idx, off);
                if (v2 > v || (v2 == v && i2 < idx)) { v = v2; idx = i2; }
            }
            if (lane == i)   { myv = v; myi = idx; }
            if (lane == idx) cv = -1.f;       // scores >= 0
        }

        // weight denom: np.sum n=8 -> serial ascending
        float S8 = 0.f;
        #pragma unroll
        for (int r = 0; r < TOPK; ++r) S8 += __shfl(myv, r);

        if (lane < TOPK) {
            const long o = (tok0 + t) * TOPK + lane;
            out[o]                     = (float)myi;   // expert_ids
            out[(long)NTOK * TOPK + o] = myv / S8;     // expert_weight
        }
    }

    const int b = blk >> 6;                  // 64 blocks per batch row
    atomicAdd(&wsum[b * NEXP + lane], auxacc);
}

__global__ void aux_finish(const float* __restrict__ wsum, float* __restrict__ out)
{
    const int lane = threadIdx.x;            // 64 threads
    float a = 0.f;
    #pragma unroll
    for (int b = 0; b < 4; ++b) {
        const float v = wsum[b * NEXP + lane] * (1.0f / 4096.0f);
        a = fmaf(v, v, a);
    }
    #pragma unroll
    for (int off = 32; off >= 1; off >>= 1)
        a += __shfl_xor(a, off);
    if (lane == 0)
        out[2L * NTOK * TOPK] = a * 0.25f * (float)NEXP * 0.01f;
}

extern "C" void kernel_launch(void* const* d_in, const int* in_sizes, int n_in,
                              void* d_out, int out_size, void* d_ws, size_t ws_size,
                              hipStream_t stream) {
    const float* h = (const float*)d_in[0];
    const float* W = (const float*)d_in[1];
    float* out  = (float*)d_out;
    float* wsum = (float*)d_ws;              // 256 f32

    hipMemsetAsync(d_ws, 0, 1024, stream);
    moe_gate_np<<<NBLK, 512, 0, stream>>>(h, W, out, wsum);
    aux_finish<<<1, 64, 0, stream>>>(wsum, out);
}

// Round 10
// 144.072 us; speedup vs baseline: 1.8262x; 1.7105x over previous
//
#include <hip/hip_runtime.h>
#include <math.h>

#define NTOK 16384      // 4 * 4096 tokens
#define DIM 2048
#define NEXP 64
#define TOPK 8
#define BT 64           // tokens per block (lane = token)
#define KC 64           // four numpy 16-blocks per stage
#define NCHUNK (DIM / KC)   // 32
#define PADK 68         // LDS row stride floats; granule stride 17 (odd) -> uniform bank groups
#define NBLK (NTOK / BT)    // 256 blocks, 1/CU, 16 waves/CU = 4/SIMD
#define EPW 4           // experts per wave (16 waves x 4 = 64)

typedef float f2 __attribute__((ext_vector_type(2)));
typedef float f4 __attribute__((ext_vector_type(4)));

// VOP3P packed f32: two independent IEEE f32 ops per instr, component-wise
// bit-identical to the scalar sequence. B comes in as an SGPR pair (src0).
__device__ __forceinline__ f2 pk_mul_sv(f2 bs, f2 av) {
    f2 d; asm("v_pk_mul_f32 %0, %1, %2" : "=v"(d) : "s"(bs), "v"(av)); return d;
}
__device__ __forceinline__ f2 pk_add(f2 a, f2 b) {
    f2 d; asm("v_pk_add_f32 %0, %1, %2" : "=v"(d) : "v"(a), "v"(b)); return d;
}

__global__ __launch_bounds__(1024, 1) void moe_gate_np(
    const float* __restrict__ h, const float* __restrict__ W,
    float* __restrict__ out, float* __restrict__ wsum)
{
#pragma clang fp contract(off)
    __shared__ float sA[BT * PADK];          // h tile [64][68]  (17.4 KB)
    __shared__ float lg[BT][NEXP + 2];       // logits -> p values (16.9 KB)

    const int tid  = threadIdx.x;            // 0..1023
    const int lane = tid & 63;               // token within tile
    const int wv   = tid >> 6;               // 0..15: expert quartet
    const int blk  = blockIdx.x;
    const long tok0 = (long)blk * BT;
    const float* hA = h + tok0 * DIM;

    // wave-uniform expert base -> scalar (s_load) W accesses
    const int e0 = __builtin_amdgcn_readfirstlane(wv) * EPW;
    const float* wb = W + (long)e0 * DIM;

    // ---- A staging map: 1 f4 per thread per stage ----
    const int rs = tid >> 4;                 // 0..63
    const int cs = (tid & 15) * 4;           // 0..60
    f4 pa = *(const f4*)(hA + (long)rs * DIM + cs);

    // accumulators: 4 experts x chain pairs (c0,c1) and (c2,c3)
    f2 acc01[EPW], acc23[EPW];
    #pragma unroll
    for (int j = 0; j < EPW; ++j) { acc01[j] = (f2)(0.f); acc23[j] = (f2)(0.f); }

    for (int kc = 0; kc < NCHUNK; ++kc) {
        __syncthreads();
        *(f4*)&sA[rs * PADK + cs] = pa;
        __syncthreads();

        if (kc + 1 < NCHUNK) {               // prefetch next A stage under compute
            const long ko = (long)(kc + 1) * KC;
            pa = *(const f4*)(hA + (long)rs * DIM + ko + cs);
        }

        // 4 numpy 16-blocks per stage, strictly ascending k
        #pragma unroll
        for (int s = 0; s < 4; ++s) {
            const int kb = kc * KC + s * 16;

            // B batch: 4 experts x 4 f4, wave-uniform -> s_load_dwordx4 (SGPRs)
            f4 B[EPW][4];
            #pragma unroll
            for (int j = 0; j < EPW; ++j)
                #pragma unroll
                for (int q = 0; q < 4; ++q)
                    B[j][q] = *(const f4*)(wb + (long)j * DIM + kb + 4 * q);

            // A: this lane's token, 16 k-values (4 x ds_read_b128, conflict-free)
            f4 af[4];
            const float* ab = &sA[lane * PADK + s * 16];
            #pragma unroll
            for (int v = 0; v < 4; ++v) af[v] = *(const f4*)(ab + 4 * v);

            f2 alo[4], ahi[4];               // .xy -> chains 0,1 ; .zw -> chains 2,3
            #pragma unroll
            for (int v = 0; v < 4; ++v) {
                alo[v] = __builtin_shufflevector(af[v], af[v], 0, 1);
                ahi[v] = __builtin_shufflevector(af[v], af[v], 2, 3);
            }

            #pragma unroll
            for (int j = 0; j < EPW; ++j) {
                f2 blo[4], bhi[4];           // uniform values -> SGPR pairs
                #pragma unroll
                for (int v = 0; v < 4; ++v) {
                    blo[v] = __builtin_shufflevector(B[j][v], B[j][v], 0, 1);
                    bhi[v] = __builtin_shufflevector(B[j][v], B[j][v], 2, 3);
                }
                f2 t;
                // chains 0,1: c = p0 + (p1 + (p2 + (p3 + c)))
                t = pk_add(pk_mul_sv(blo[3], alo[3]), acc01[j]);
                t = pk_add(pk_mul_sv(blo[2], alo[2]), t);
                t = pk_add(pk_mul_sv(blo[1], alo[1]), t);
                acc01[j] = pk_add(pk_mul_sv(blo[0], alo[0]), t);
                // chains 2,3
                t = pk_add(pk_mul_sv(bhi[3], ahi[3]), acc23[j]);
                t = pk_add(pk_mul_sv(bhi[2], ahi[2]), t);
                t = pk_add(pk_mul_sv(bhi[1], ahi[1]), t);
                acc23[j] = pk_add(pk_mul_sv(bhi[0], ahi[0]), t);
            }
        }
    }

    // horizontal combine: (c0+c2)+(c1+c3)  (npyv_sum_f32 SSE2 order)
    #pragma unroll
    for (int j = 0; j < EPW; ++j) {
        f2 s2 = pk_add(acc01[j], acc23[j]);   // (c0+c2, c1+c3)
        lg[lane][e0 + j] = s2.x + s2.y;
    }
    __syncthreads();

    // ---- per-token f32 softmax + stable top-8, numpy rounding orders ----
    float auxacc = 0.f;

    for (int tt = 0; tt < 4; ++tt) {
        const int t = wv * 4 + tt;            // 16 waves x 4 tokens
        const float s = lg[t][lane];          // lane = expert here

        float m = s;                          // max: exact, order-independent
        #pragma unroll
        for (int off = 32; off >= 1; off >>= 1)
            m = fmaxf(m, __shfl_xor(m, off));

        const float p = expf(s - m);
        lg[t][lane] = p;                      // own wave's rows only
        __asm__ volatile("" ::: "memory");    // compiler barrier; DS in-order per wave

        // np.sum pairwise, n=64: 8 stride-8 serial chains + fixed combine
        float r0s = lg[t][0], r1s = lg[t][1], r2s = lg[t][2], r3s = lg[t][3];
        float r4s = lg[t][4], r5s = lg[t][5], r6s = lg[t][6], r7s = lg[t][7];
        #pragma unroll
        for (int i = 1; i < 8; ++i) {
            r0s += lg[t][8 * i + 0]; r1s += lg[t][8 * i + 1];
            r2s += lg[t][8 * i + 2]; r3s += lg[t][8 * i + 3];
            r4s += lg[t][8 * i + 4]; r5s += lg[t][8 * i + 5];
            r6s += lg[t][8 * i + 6]; r7s += lg[t][8 * i + 7];
        }
        const float S = ((r0s + r1s) + (r2s + r3s)) + ((r4s + r5s) + (r6s + r7s));

        const float score = p / S;            // IEEE f32 divide, matches np
        auxacc += score;

        // stable top-8: max with lowest-index tie-break (stable argsort)
        float cv = score;
        float myv = 0.f;
        int   myi = 0;
        #pragma unroll
        for (int i = 0; i < TOPK; ++i) {
            float v = cv;
            int idx = lane;
            #pragma unroll
            for (int off = 32; off >= 1; off >>= 1) {
                float v2 = __shfl_xor(v, off);
                int   i2 = __shfl_xor(idx, off);
                if (v2 > v || (v2 == v && i2 < idx)) { v = v2; idx = i2; }
            }
            if (lane == i)   { myv = v; myi = idx; }
            if (lane == idx) cv = -1.f;       // scores >= 0
        }

        // weight denom: np.sum n=8 -> serial ascending
        float S8 = 0.f;
        #pragma unroll
        for (int r = 0; r < TOPK; ++r) S8 += __shfl(myv, r);

        if (lane < TOPK) {
            const long o = (tok0 + t) * TOPK + lane;
            out[o]                     = (float)myi;   // expert_ids
            out[(long)NTOK * TOPK + o] = myv / S8;     // expert_weight
        }
    }

    const int b = blk >> 6;                  // 64 blocks per batch row
    atomicAdd(&wsum[b * NEXP + lane], auxacc);
}

__global__ void aux_finish(const float* __restrict__ wsum, float* __restrict__ out)
{
    const int lane = threadIdx.x;            // 64 threads
    float a = 0.f;
    #pragma unroll
    for (int b = 0; b < 4; ++b) {
        const float v = wsum[b * NEXP + lane] * (1.0f / 4096.0f);
        a = fmaf(v, v, a);
    }
    #pragma unroll
    for (int off = 32; off >= 1; off >>= 1)
        a += __shfl_xor(a, off);
    if (lane == 0)
        out[2L * NTOK * TOPK] = a * 0.25f * (float)NEXP * 0.01f;
}

extern "C" void kernel_launch(void* const* d_in, const int* in_sizes, int n_in,
                              void* d_out, int out_size, void* d_ws, size_t ws_size,
                              hipStream_t stream) {
    const float* h = (const float*)d_in[0];
    const float* W = (const float*)d_in[1];
    float* out  = (float*)d_out;
    float* wsum = (float*)d_ws;              // 256 f32

    hipMemsetAsync(d_ws, 0, 1024, stream);
    moe_gate_np<<<NBLK, 1024, 0, stream>>>(h, W, out, wsum);
    aux_finish<<<1, 64, 0, stream>>>(wsum, out);
}